// Round 9
// baseline (133.352 us; speedup 1.0000x reference)
//
#include <hip/hip_runtime.h>

#define N_NODES 100000
#define N_EDGES 1600000
#define D_FEAT 32

#define BSH 7                 // bucket = dst >> 7  (128 nodes per bucket)
#define BMASK 127
#define NB 782                // ceil(100000/128)
#define CAPB 2432             // per-bucket capacity (mean 2048, ~8.5 sigma pad)

#define P1_BS 512
#define P1_TILE 4096          // 8 edges/thread
#define P1_CAP 16             // staging per bucket per block (mean ~5.2)

// ws layout (4-byte words):
//   cursorA [1024]        int    per-bucket RELATIVE fill cursors (memset 0)
//   dinv    [N_NODES]     float
//   pairs   [NB*CAPB]     int    packed (src<<7)|(dst&127), bucket-grouped
//   sfeat   [N_NODES*16]  uint   bf16-packed feat*dinv (2 feats per uint)

static __device__ __forceinline__ unsigned pack_bf16(float a, float b) {
    unsigned ua = __float_as_uint(a);
    unsigned ub = __float_as_uint(b);
    ua = (ua + 0x7FFFu + ((ua >> 16) & 1u)) >> 16;   // RNE
    ub = (ub + 0x7FFFu + ((ub >> 16) & 1u)) >> 16;
    return (ua & 0xFFFFu) | (ub << 16);
}

// Pass 1: bucket edges by dst>>7 with LDS staging -> coalesced runs into
// fixed per-bucket regions (cursors are relative; region base = b*CAPB).
__global__ void __launch_bounds__(P1_BS)
bucket_kernel(const int* __restrict__ edge_src,
              const int* __restrict__ edge_dst,
              int* __restrict__ cursorA,
              int* __restrict__ pairs, int n_edges) {
    __shared__ int s_cnt[NB];
    __shared__ int s_base[NB];
    __shared__ int s_off[NB + 1];
    __shared__ int s_buf[NB * P1_CAP];   // 782*16*4 = 50 KB

    int tile = blockIdx.x * P1_TILE;
    if (tile >= n_edges) return;

    for (int b = threadIdx.x; b < NB; b += P1_BS) s_cnt[b] = 0;
    __syncthreads();

    const int4* src4 = reinterpret_cast<const int4*>(edge_src);
    const int4* dst4 = reinterpret_cast<const int4*>(edge_dst);
    int tileq = blockIdx.x * (P1_TILE / 4);
    #pragma unroll
    for (int j = 0; j < P1_TILE / 4 / P1_BS; ++j) {
        int iq = tileq + j * P1_BS + threadIdx.x;
        if (iq * 4 < n_edges) {
            int4 sv = src4[iq];
            int4 dv = dst4[iq];
            int ss[4] = {sv.x, sv.y, sv.z, sv.w};
            int dd[4] = {dv.x, dv.y, dv.z, dv.w};
            #pragma unroll
            for (int u = 0; u < 4; ++u) {
                int b = dd[u] >> BSH;
                int packed = (ss[u] << BSH) | (dd[u] & BMASK);
                int p = atomicAdd(&s_cnt[b], 1);
                if (p < P1_CAP) {
                    s_buf[b * P1_CAP + p] = packed;
                } else {
                    int gp = atomicAdd(&cursorA[b], 1);   // rare overflow
                    if (gp < CAPB) pairs[b * CAPB + gp] = packed;
                }
            }
        }
    }
    __syncthreads();

    for (int b = threadIdx.x; b < NB; b += P1_BS) {
        int c = min(s_cnt[b], P1_CAP);
        s_base[b] = b * CAPB + atomicAdd(&cursorA[b], c);
        s_cnt[b] = c;
    }
    __syncthreads();
    if (threadIdx.x == 0) {
        int acc = 0;
        for (int b = 0; b < NB; ++b) { s_off[b] = acc; acc += s_cnt[b]; }
        s_off[NB] = acc;
    }
    __syncthreads();

    int total = s_off[NB];
    for (int t = threadIdx.x; t < total; t += P1_BS) {
        int lo = 0, hi = NB;
        while (hi - lo > 1) {
            int mid = (lo + hi) >> 1;
            if (t >= s_off[mid]) lo = mid; else hi = mid;
        }
        int idx = t - s_off[lo];
        pairs[s_base[lo] + idx] = s_buf[lo * P1_CAP + idx];
    }
}

// Pass 2: per-bucket LDS histogram -> dinv + bf16 sfeat rows.
__global__ void __launch_bounds__(256)
hist_kernel(const int* __restrict__ pairs,
            const int* __restrict__ cursorA,
            const float* __restrict__ feat,
            float* __restrict__ dinv,
            unsigned* __restrict__ sfeat) {
    __shared__ int h[128];
    __shared__ float dv_s[128];
    int b = blockIdx.x;
    int t = threadIdx.x;
    int base = b * CAPB;
    int cnt = min(cursorA[b], CAPB);

    if (t < 128) h[t] = 0;
    __syncthreads();
    for (int i = t; i < cnt; i += 256)
        atomicAdd(&h[pairs[base + i] & BMASK], 1);
    __syncthreads();
    if (t < 128) {
        float dvv = rsqrtf(fmaxf((float)h[t], 1.0f));
        dv_s[t] = dvv;
        int node = (b << BSH) + t;
        if (node < N_NODES) dinv[node] = dvv;
    }
    __syncthreads();

    const float4* feat4 = reinterpret_cast<const float4*>(feat);
    uint4* sf4 = reinterpret_cast<uint4*>(sfeat);
    for (int idx = t; idx < 128 * 4; idx += 256) {
        int nl = idx >> 2;
        int q = idx & 3;
        int node = (b << BSH) + nl;
        if (node >= N_NODES) continue;
        float dvv = dv_s[nl];
        float4 fa = feat4[node * 8 + 2 * q];
        float4 fb = feat4[node * 8 + 2 * q + 1];
        uint4 pk;
        pk.x = pack_bf16(fa.x * dvv, fa.y * dvv);
        pk.y = pack_bf16(fa.z * dvv, fa.w * dvv);
        pk.z = pack_bf16(fb.x * dvv, fb.y * dvv);
        pk.w = pack_bf16(fb.z * dvv, fb.w * dvv);
        sf4[node * 4 + q] = pk;
    }
}

// Pass 3: fused counting-sort + gather + Bernstein epilogue.
// Block = bucket. Sort pairs in LDS; gather sfeat rows using LDS indices.
__global__ void __launch_bounds__(256)
sortgather_kernel(const int* __restrict__ pairs,
                  const int* __restrict__ cursorA,
                  const float* __restrict__ feat,
                  const unsigned* __restrict__ sfeat,
                  float* __restrict__ out) {
    __shared__ int buf[CAPB];     // 9.5 KB
    __shared__ int outb[CAPB];    // 9.5 KB
    __shared__ int h[128];
    __shared__ int sc[128];
    __shared__ int cur[128];
    __shared__ int exs[128];
    __shared__ int cnl[128];
    __shared__ float dv_s[128];

    int b = blockIdx.x;
    int t = threadIdx.x;
    int base = b * CAPB;
    int cnt = min(cursorA[b], CAPB);

    if (t < 128) h[t] = 0;
    __syncthreads();
    for (int i = t; i < cnt; i += 256) {
        int p = pairs[base + i];
        buf[i] = p;
        atomicAdd(&h[p & BMASK], 1);
    }
    __syncthreads();

    // exclusive scan of h (128 bins)
    int v = 0;
    if (t < 128) { v = h[t]; sc[t] = v; }
    __syncthreads();
    for (int off = 1; off < 128; off <<= 1) {
        int x = 0;
        if (t < 128 && t >= off) x = sc[t - off];
        __syncthreads();
        if (t < 128) sc[t] += x;
        __syncthreads();
    }
    if (t < 128) {
        int ex = sc[t] - v;
        cur[t] = ex;
        exs[t] = ex;
        cnl[t] = v;
        dv_s[t] = rsqrtf(fmaxf((float)v, 1.0f));
    }
    __syncthreads();

    for (int i = t; i < cnt; i += 256) {
        int p = buf[i];
        int pos = atomicAdd(&cur[p & BMASK], 1);
        outb[pos] = p >> BSH;        // global src index
    }
    __syncthreads();

    // Gather phase: 128 nodes x 4 feature-quads = 512 items
    const uint4* sf4 = reinterpret_cast<const uint4*>(sfeat);
    const float4* feat4 = reinterpret_cast<const float4*>(feat);
    float4* out4 = reinterpret_cast<float4*>(out);

    #define ACC(r)                                                 \
        a0 += __uint_as_float((r).x << 16);                        \
        a1 += __uint_as_float((r).x & 0xFFFF0000u);                \
        a2 += __uint_as_float((r).y << 16);                        \
        a3 += __uint_as_float((r).y & 0xFFFF0000u);                \
        a4 += __uint_as_float((r).z << 16);                        \
        a5 += __uint_as_float((r).z & 0xFFFF0000u);                \
        a6 += __uint_as_float((r).w << 16);                        \
        a7 += __uint_as_float((r).w & 0xFFFF0000u);

    #pragma unroll
    for (int pass = 0; pass < 2; ++pass) {
        int item = t + pass * 256;
        int nl = item >> 2;
        int q = item & 3;
        int node = (b << BSH) + nl;
        if (node >= N_NODES) continue;
        int k = exs[nl];
        int en = k + cnl[nl];
        float a0 = 0.f, a1 = 0.f, a2 = 0.f, a3 = 0.f;
        float a4 = 0.f, a5 = 0.f, a6 = 0.f, a7 = 0.f;
        for (; k + 3 < en; k += 4) {
            int s0 = outb[k],     s1 = outb[k + 1];
            int s2 = outb[k + 2], s3 = outb[k + 3];
            uint4 r0 = sf4[s0 * 4 + q];
            uint4 r1 = sf4[s1 * 4 + q];
            uint4 r2 = sf4[s2 * 4 + q];
            uint4 r3 = sf4[s3 * 4 + q];
            ACC(r0) ACC(r1) ACC(r2) ACC(r3)
        }
        for (; k < en; ++k) {
            uint4 r = sf4[outb[k] * 4 + q];
            ACC(r)
        }
        float dvn = dv_s[nl];
        float4 fa = feat4[node * 8 + 2 * q];
        float4 fb = feat4[node * 8 + 2 * q + 1];
        float4 oa, ob;
        float y;
        y = 0.5f * (fa.x - a0 * dvn); oa.x = 2.0f * y * (fa.x - y);
        y = 0.5f * (fa.y - a1 * dvn); oa.y = 2.0f * y * (fa.y - y);
        y = 0.5f * (fa.z - a2 * dvn); oa.z = 2.0f * y * (fa.z - y);
        y = 0.5f * (fa.w - a3 * dvn); oa.w = 2.0f * y * (fa.w - y);
        y = 0.5f * (fb.x - a4 * dvn); ob.x = 2.0f * y * (fb.x - y);
        y = 0.5f * (fb.y - a5 * dvn); ob.y = 2.0f * y * (fb.y - y);
        y = 0.5f * (fb.z - a6 * dvn); ob.z = 2.0f * y * (fb.z - y);
        y = 0.5f * (fb.w - a7 * dvn); ob.w = 2.0f * y * (fb.w - y);
        out4[node * 8 + 2 * q] = oa;
        out4[node * 8 + 2 * q + 1] = ob;
    }
    #undef ACC
}

extern "C" void kernel_launch(void* const* d_in, const int* in_sizes, int n_in,
                              void* d_out, int out_size, void* d_ws, size_t ws_size,
                              hipStream_t stream) {
    const float* feat = (const float*)d_in[0];
    const int* edge_src = (const int*)d_in[1];
    const int* edge_dst = (const int*)d_in[2];
    float* out = (float*)d_out;

    int* ws = (int*)d_ws;
    int* cursorA    = ws;                              // 1024
    float* dinv     = (float*)(cursorA + 1024);        // N_NODES
    int* pairs      = (int*)(dinv + N_NODES);          // NB*CAPB
    unsigned* sfeat = (unsigned*)(pairs + NB * CAPB);  // N_NODES*16

    hipMemsetAsync(cursorA, 0, 1024 * sizeof(int), stream);
    {
        int blocks = (N_EDGES + P1_TILE - 1) / P1_TILE;   // 391
        bucket_kernel<<<blocks, P1_BS, 0, stream>>>(edge_src, edge_dst,
                                                    cursorA, pairs, N_EDGES);
    }
    hist_kernel<<<NB, 256, 0, stream>>>(pairs, cursorA, feat, dinv, sfeat);
    sortgather_kernel<<<NB, 256, 0, stream>>>(pairs, cursorA, feat, sfeat, out);
}